// Round 4
// baseline (229.214 us; speedup 1.0000x reference)
//
#include <hip/hip_runtime.h>
#include <hip/hip_bf16.h>
#include <math.h>

// ---------------------------------------------------------------------------
// Problem shapes
// ---------------------------------------------------------------------------
#define NN 400000
#define GG 1024
#define E1 7
#define E2 70
#define E3 300

// Output layout (flat f32)
#define OFF_L1 0
#define OFF_L2 7168
#define OFF_L3 78848
#define OFF_P1 386048
#define OFF_G  393216

// ws layout (float offsets)
#define WS_MEAN   0          // gfm  [1024*256]
#define WS_G      262144     // gact [1024*256]
#define WS_P1     524288     // p1   [1024*7]
#define WS_P2     531456     // p2   [1024*70]
#define WS_PART   603136     // partials [2048*256]
#define WS_BOUNDS 1127424    // bounds [1025] (as int)

// ---------------------------------------------------------------------------
// Kernel 0: segment bounds. bounds[i] = lower_bound(bidx, i), i in [0,1024].
// ---------------------------------------------------------------------------
__global__ __launch_bounds__(256) void bounds_kernel(
    const int* __restrict__ bidx, int* __restrict__ bounds) {
  const int i = blockIdx.x * 256 + threadIdx.x;
  if (i > GG) return;
  int lo = 0, hi = NN;
  while (lo < hi) {
    int mid = (lo + hi) >> 1;
    if (bidx[mid] < i) lo = mid + 1; else hi = mid;
  }
  bounds[i] = lo;
}

// ---------------------------------------------------------------------------
// Kernel 1a: partial sums. 2048 blocks = (graph g, half h). Each of the 4
// waves sums a CONTIGUOUS row range with 8 independent float4 accumulators
// (8KB in flight per wave). Writes partial[g*2+h][256].
// ---------------------------------------------------------------------------
__global__ __launch_bounds__(256) void seg_partial_kernel(
    const float* __restrict__ emb, const int* __restrict__ bounds,
    float* __restrict__ part) {
  const int g = blockIdx.x >> 1;
  const int h = blockIdx.x & 1;
  const int tid = threadIdx.x;
  const int wave = tid >> 6, lane = tid & 63;

  const int start = bounds[g], end = bounds[g + 1];
  const int cnt = end - start;
  const int mid = start + (cnt >> 1);
  // this block's half
  const int hs = h ? mid : start;
  const int he = h ? end : mid;
  const int hn = he - hs;
  // this wave's contiguous quarter of the half
  const int q0 = hs + (hn * wave) / 4;
  const int q1 = hs + (hn * (wave + 1)) / 4;

  const float4* __restrict__ p = (const float4*)emb + (size_t)q0 * 64 + lane;
  int n = q1 - q0;

  float4 a0 = make_float4(0.f, 0.f, 0.f, 0.f);
  float4 a1 = a0, a2 = a0, a3 = a0, a4 = a0, a5 = a0, a6 = a0, a7 = a0;

  for (; n >= 8; n -= 8, p += 512) {
    float4 v0 = p[0];
    float4 v1 = p[64];
    float4 v2 = p[128];
    float4 v3 = p[192];
    float4 v4 = p[256];
    float4 v5 = p[320];
    float4 v6 = p[384];
    float4 v7 = p[448];
    a0.x += v0.x; a0.y += v0.y; a0.z += v0.z; a0.w += v0.w;
    a1.x += v1.x; a1.y += v1.y; a1.z += v1.z; a1.w += v1.w;
    a2.x += v2.x; a2.y += v2.y; a2.z += v2.z; a2.w += v2.w;
    a3.x += v3.x; a3.y += v3.y; a3.z += v3.z; a3.w += v3.w;
    a4.x += v4.x; a4.y += v4.y; a4.z += v4.z; a4.w += v4.w;
    a5.x += v5.x; a5.y += v5.y; a5.z += v5.z; a5.w += v5.w;
    a6.x += v6.x; a6.y += v6.y; a6.z += v6.z; a6.w += v6.w;
    a7.x += v7.x; a7.y += v7.y; a7.z += v7.z; a7.w += v7.w;
  }
  for (; n > 0; --n, p += 64) {
    float4 v = p[0];
    a0.x += v.x; a0.y += v.y; a0.z += v.z; a0.w += v.w;
  }
  // pairwise combine
  a0.x += a1.x; a0.y += a1.y; a0.z += a1.z; a0.w += a1.w;
  a2.x += a3.x; a2.y += a3.y; a2.z += a3.z; a2.w += a3.w;
  a4.x += a5.x; a4.y += a5.y; a4.z += a5.z; a4.w += a5.w;
  a6.x += a7.x; a6.y += a7.y; a6.z += a7.z; a6.w += a7.w;
  a0.x += a2.x; a0.y += a2.y; a0.z += a2.z; a0.w += a2.w;
  a4.x += a6.x; a4.y += a6.y; a4.z += a6.z; a4.w += a6.w;
  a0.x += a4.x; a0.y += a4.y; a0.z += a4.z; a0.w += a4.w;

  // cross-wave combine in LDS
  __shared__ float4 red[4][64];
  red[wave][lane] = a0;
  __syncthreads();
  if (tid < 64) {
    float4 p0 = red[0][tid], p1 = red[1][tid], p2 = red[2][tid], p3 = red[3][tid];
    float4 s;
    s.x = (p0.x + p1.x) + (p2.x + p3.x);
    s.y = (p0.y + p1.y) + (p2.y + p3.y);
    s.z = (p0.z + p1.z) + (p2.z + p3.z);
    s.w = (p0.w + p1.w) + (p2.w + p3.w);
    ((float4*)part)[(size_t)blockIdx.x * 64 + tid] = s;
  }
}

// ---------------------------------------------------------------------------
// Kernel 1b: mean = (partial[g][0] + partial[g][1]) / cnt
// ---------------------------------------------------------------------------
__global__ __launch_bounds__(256) void seg_mean_kernel(
    const float* __restrict__ part, const int* __restrict__ bounds,
    float* __restrict__ gf) {
  const int g = blockIdx.x;
  const int j = threadIdx.x;
  const int cnt = bounds[g + 1] - bounds[g];
  const float inv = 1.0f / (float)max(cnt, 1);
  const float v = (part[(size_t)(g * 2) * 256 + j] +
                   part[(size_t)(g * 2 + 1) * 256 + j]) * inv;
  gf[(size_t)g * 256 + j] = v;
}

// ---------------------------------------------------------------------------
// MLP stage kernels — BYTE-IDENTICAL to R3 for attribution.
// ---------------------------------------------------------------------------
__device__ __forceinline__ float gelu_exact(float v) {
  return 0.5f * v * (1.0f + erff(v * 0.70710678118654752f));
}

__global__ __launch_bounds__(256) void pool_kernel(
    const float* __restrict__ gfm, const float* __restrict__ W,
    const float* __restrict__ B, float* __restrict__ gact,
    float* __restrict__ out) {
  const int r0 = blockIdx.x * 2;
  const int j = threadIdx.x;
  __shared__ float xs[2][256];
  xs[0][j] = gfm[r0 * 256 + j];
  xs[1][j] = gfm[(r0 + 1) * 256 + j];
  __syncthreads();
  float a0 = 0.f, a1 = 0.f;
#pragma unroll 8
  for (int k = 0; k < 256; ++k) {
    const float w = W[k * 256 + j];
    a0 += xs[0][k] * w;
    a1 += xs[1][k] * w;
  }
  const float bj = B[j];
  a0 = gelu_exact(a0 + bj);
  a1 = gelu_exact(a1 + bj);
  gact[r0 * 256 + j] = a0;
  gact[(r0 + 1) * 256 + j] = a1;
  out[OFF_G + r0 * 256 + j] = a0;
  out[OFF_G + (r0 + 1) * 256 + j] = a1;
}

__global__ __launch_bounds__(256) void ec1_kernel(
    const float* __restrict__ gact,
    const float* __restrict__ W1, const float* __restrict__ B1,
    const float* __restrict__ W2, const float* __restrict__ B2,
    float* __restrict__ out, float* __restrict__ p1) {
  const int r0 = blockIdx.x * 2;
  const int t = threadIdx.x;
  const int r = t >> 7, j = t & 127;
  __shared__ float xs[2][256];
  __shared__ float hs[2][128];
  __shared__ float os[2][E1];
  xs[0][t] = gact[r0 * 256 + t];
  xs[1][t] = gact[(r0 + 1) * 256 + t];
  __syncthreads();
  {
    float a = 0.f;
#pragma unroll 8
    for (int k = 0; k < 256; ++k) a += xs[r][k] * W1[k * 128 + j];
    hs[r][j] = gelu_exact(a + B1[j]);
  }
  __syncthreads();
  if (t < 2 * E1) {
    const int r2 = t / E1, j2 = t - r2 * E1;
    float acc = B2[j2];
#pragma unroll 8
    for (int k = 0; k < 128; ++k) acc += hs[r2][k] * W2[k * E1 + j2];
    os[r2][j2] = acc;
    out[OFF_L1 + (r0 + r2) * E1 + j2] = acc;
  }
  __syncthreads();
  if (t < 2) {
    float m = os[t][0];
    for (int q = 1; q < E1; ++q) m = fmaxf(m, os[t][q]);
    float s = 0.f;
    for (int q = 0; q < E1; ++q) { float e = expf(os[t][q] - m); os[t][q] = e; s += e; }
    const float inv = 1.0f / s;
    for (int q = 0; q < E1; ++q) os[t][q] *= inv;
  }
  __syncthreads();
  if (t < 2 * E1) {
    const int r2 = t / E1, j2 = t - r2 * E1;
    const float v = os[r2][j2];
    out[OFF_P1 + (r0 + r2) * E1 + j2] = v;
    p1[(r0 + r2) * E1 + j2] = v;
  }
}

__global__ __launch_bounds__(256) void ec2_kernel(
    const float* __restrict__ gact, const float* __restrict__ p1,
    const float* __restrict__ W1, const float* __restrict__ B1,
    const float* __restrict__ W2, const float* __restrict__ B2,
    float* __restrict__ out, float* __restrict__ p2) {
  const int K1 = 256 + E1;  // 263
  const int r0 = blockIdx.x * 2;
  const int t = threadIdx.x;
  const int r = t >> 7, j = t & 127;
  __shared__ float xs[2][263];
  __shared__ float hs[2][128];
  __shared__ float os[2][E2];
  for (int idx = t; idx < 2 * K1; idx += 256) {
    const int rr = idx / K1, k = idx - rr * K1;
    xs[rr][k] = (k < 256) ? gact[(r0 + rr) * 256 + k]
                          : p1[(r0 + rr) * E1 + (k - 256)];
  }
  __syncthreads();
  {
    float a = 0.f;
#pragma unroll 8
    for (int k = 0; k < K1; ++k) a += xs[r][k] * W1[k * 128 + j];
    hs[r][j] = gelu_exact(a + B1[j]);
  }
  __syncthreads();
  if (t < 2 * E2) {
    const int r2 = t / E2, j2 = t - r2 * E2;
    float acc = B2[j2];
#pragma unroll 8
    for (int k = 0; k < 128; ++k) acc += hs[r2][k] * W2[k * E2 + j2];
    os[r2][j2] = acc;
    out[OFF_L2 + (r0 + r2) * E2 + j2] = acc;
  }
  __syncthreads();
  if (t < 2) {
    float m = os[t][0];
    for (int q = 1; q < E2; ++q) m = fmaxf(m, os[t][q]);
    float s = 0.f;
    for (int q = 0; q < E2; ++q) { float e = expf(os[t][q] - m); os[t][q] = e; s += e; }
    const float inv = 1.0f / s;
    for (int q = 0; q < E2; ++q) os[t][q] *= inv;
  }
  __syncthreads();
  if (t < 2 * E2) {
    const int r2 = t / E2, j2 = t - r2 * E2;
    p2[(r0 + r2) * E2 + j2] = os[r2][j2];
  }
}

__global__ __launch_bounds__(256) void ec3_kernel(
    const float* __restrict__ gact, const float* __restrict__ p1,
    const float* __restrict__ p2,
    const float* __restrict__ W1, const float* __restrict__ B1,
    const float* __restrict__ W2, const float* __restrict__ B2,
    float* __restrict__ out) {
  const int K1 = 256 + E1 + E2;  // 333
  const int r0 = blockIdx.x * 2;
  const int t = threadIdx.x;
  const int r = t >> 7, j = t & 127;
  __shared__ float xs[2][333];
  __shared__ float hs[2][128];
  for (int idx = t; idx < 2 * K1; idx += 256) {
    const int rr = idx / K1, k = idx - rr * K1;
    float v;
    if (k < 256)            v = gact[(r0 + rr) * 256 + k];
    else if (k < 256 + E1)  v = p1[(r0 + rr) * E1 + (k - 256)];
    else                    v = p2[(r0 + rr) * E2 + (k - 256 - E1)];
    xs[rr][k] = v;
  }
  __syncthreads();
  {
    float a = 0.f;
#pragma unroll 8
    for (int k = 0; k < K1; ++k) a += xs[r][k] * W1[k * 128 + j];
    hs[r][j] = gelu_exact(a + B1[j]);
  }
  __syncthreads();
  for (int idx = t; idx < 2 * E3; idx += 256) {
    const int r2 = idx / E3, j2 = idx - r2 * E3;
    float acc = B2[j2];
#pragma unroll 8
    for (int k = 0; k < 128; ++k) acc += hs[r2][k] * W2[k * E3 + j2];
    out[OFF_L3 + (r0 + r2) * E3 + j2] = acc;
  }
}

// ---------------------------------------------------------------------------
extern "C" void kernel_launch(void* const* d_in, const int* in_sizes, int n_in,
                              void* d_out, int out_size, void* d_ws, size_t ws_size,
                              hipStream_t stream) {
  const float* emb    = (const float*)d_in[0];
  const int*   bidx   = (const int*)d_in[1];
  const float* pool_w = (const float*)d_in[2];
  const float* pool_b = (const float*)d_in[3];
  const float* w11    = (const float*)d_in[4];
  const float* b11    = (const float*)d_in[5];
  const float* w12    = (const float*)d_in[6];
  const float* b12    = (const float*)d_in[7];
  const float* w21    = (const float*)d_in[8];
  const float* b21    = (const float*)d_in[9];
  const float* w22    = (const float*)d_in[10];
  const float* b22    = (const float*)d_in[11];
  const float* w31    = (const float*)d_in[12];
  const float* b31    = (const float*)d_in[13];
  const float* w32    = (const float*)d_in[14];
  const float* b32    = (const float*)d_in[15];
  float* out = (float*)d_out;
  float* ws  = (float*)d_ws;
  float* gfm    = ws + WS_MEAN;
  float* gact   = ws + WS_G;
  float* p1     = ws + WS_P1;
  float* p2     = ws + WS_P2;
  float* part   = ws + WS_PART;
  int*   bounds = (int*)(ws + WS_BOUNDS);

  bounds_kernel<<<5, 256, 0, stream>>>(bidx, bounds);
  seg_partial_kernel<<<GG * 2, 256, 0, stream>>>(emb, bounds, part);
  seg_mean_kernel<<<GG, 256, 0, stream>>>(part, bounds, gfm);
  pool_kernel<<<GG / 2, 256, 0, stream>>>(gfm, pool_w, pool_b, gact, out);
  ec1_kernel<<<GG / 2, 256, 0, stream>>>(gact, w11, b11, w12, b12, out, p1);
  ec2_kernel<<<GG / 2, 256, 0, stream>>>(gact, p1, w21, b21, w22, b22, out, p2);
  ec3_kernel<<<GG / 2, 256, 0, stream>>>(gact, p1, p2, w31, b31, w32, b32, out);
}

// Round 5
// 197.032 us; speedup vs baseline: 1.1633x; 1.1633x over previous
//
#include <hip/hip_runtime.h>
#include <hip/hip_bf16.h>
#include <math.h>

// ---------------------------------------------------------------------------
// Problem shapes
// ---------------------------------------------------------------------------
#define NN 400000
#define GG 1024
#define E1 7
#define E2 70
#define E3 300

// Output layout (flat f32)
#define OFF_L1 0
#define OFF_L2 7168
#define OFF_L3 78848
#define OFF_P1 386048
#define OFF_G  393216

__device__ __forceinline__ float gelu_exact(float v) {
  return 0.5f * v * (1.0f + erff(v * 0.70710678118654752f));
}

// ---------------------------------------------------------------------------
// ONE fused kernel: block b owns graphs {2b, 2b+1}.
//   Phase A: bounds via in-block binary search (bidx sorted).
//   Phase B: segment mean (contiguous per-wave streams, unroll-8 float4).
//   Phase C: full MLP cascade on the block's 2 rows, activations in LDS.
// 512 blocks x 256 threads. No workspace, no inter-block communication.
// ---------------------------------------------------------------------------
__global__ __launch_bounds__(256) void fused_kernel(
    const float* __restrict__ emb, const int* __restrict__ bidx,
    const float* __restrict__ pool_w, const float* __restrict__ pool_b,
    const float* __restrict__ w11, const float* __restrict__ b11,
    const float* __restrict__ w12, const float* __restrict__ b12,
    const float* __restrict__ w21, const float* __restrict__ b21,
    const float* __restrict__ w22, const float* __restrict__ b22,
    const float* __restrict__ w31, const float* __restrict__ b31,
    const float* __restrict__ w32, const float* __restrict__ b32,
    float* __restrict__ out) {
  const int g0 = blockIdx.x * 2;
  const int tid = threadIdx.x;
  const int wave = tid >> 6, lane = tid & 63;

  __shared__ int seg[3];
  __shared__ float xs[2][336];   // concat activations: g | p1 | p2 (K up to 333)
  __shared__ float hs[2][128];   // hidden
  __shared__ float os[2][72];    // head logits (up to E2) for softmax
  __shared__ float4 red[4][64];  // cross-wave reduction

  // ---- Phase A: segment bounds ----
  if (tid < 3) {
    const int target = g0 + tid;
    int lo = 0, hi = NN;
    while (lo < hi) {
      int mid = (lo + hi) >> 1;
      if (bidx[mid] < target) lo = mid + 1; else hi = mid;
    }
    seg[tid] = lo;
  }
  __syncthreads();

  // ---- Phase B: mean for each of the 2 graphs ----
  for (int gg = 0; gg < 2; ++gg) {
    const int start = seg[gg], end = seg[gg + 1];
    const int hn = end - start;
    // this wave's contiguous quarter
    const int q0 = start + (hn * wave) / 4;
    const int q1 = start + (hn * (wave + 1)) / 4;
    const float4* __restrict__ p = (const float4*)emb + (size_t)q0 * 64 + lane;
    int n = q1 - q0;

    float4 a0 = make_float4(0.f, 0.f, 0.f, 0.f);
    float4 a1 = a0, a2 = a0, a3 = a0, a4 = a0, a5 = a0, a6 = a0, a7 = a0;
    for (; n >= 8; n -= 8, p += 512) {
      float4 v0 = p[0];
      float4 v1 = p[64];
      float4 v2 = p[128];
      float4 v3 = p[192];
      float4 v4 = p[256];
      float4 v5 = p[320];
      float4 v6 = p[384];
      float4 v7 = p[448];
      a0.x += v0.x; a0.y += v0.y; a0.z += v0.z; a0.w += v0.w;
      a1.x += v1.x; a1.y += v1.y; a1.z += v1.z; a1.w += v1.w;
      a2.x += v2.x; a2.y += v2.y; a2.z += v2.z; a2.w += v2.w;
      a3.x += v3.x; a3.y += v3.y; a3.z += v3.z; a3.w += v3.w;
      a4.x += v4.x; a4.y += v4.y; a4.z += v4.z; a4.w += v4.w;
      a5.x += v5.x; a5.y += v5.y; a5.z += v5.z; a5.w += v5.w;
      a6.x += v6.x; a6.y += v6.y; a6.z += v6.z; a6.w += v6.w;
      a7.x += v7.x; a7.y += v7.y; a7.z += v7.z; a7.w += v7.w;
    }
    for (; n > 0; --n, p += 64) {
      float4 v = p[0];
      a0.x += v.x; a0.y += v.y; a0.z += v.z; a0.w += v.w;
    }
    a0.x += a1.x; a0.y += a1.y; a0.z += a1.z; a0.w += a1.w;
    a2.x += a3.x; a2.y += a3.y; a2.z += a3.z; a2.w += a3.w;
    a4.x += a5.x; a4.y += a5.y; a4.z += a5.z; a4.w += a5.w;
    a6.x += a7.x; a6.y += a7.y; a6.z += a7.z; a6.w += a7.w;
    a0.x += a2.x; a0.y += a2.y; a0.z += a2.z; a0.w += a2.w;
    a4.x += a6.x; a4.y += a6.y; a4.z += a6.z; a4.w += a6.w;
    a0.x += a4.x; a0.y += a4.y; a0.z += a4.z; a0.w += a4.w;

    red[wave][lane] = a0;
    __syncthreads();
    if (tid < 64) {
      float4 p0 = red[0][tid], p1v = red[1][tid], p2v = red[2][tid], p3v = red[3][tid];
      const float inv = 1.0f / (float)max(hn, 1);
      xs[gg][4 * tid + 0] = ((p0.x + p1v.x) + (p2v.x + p3v.x)) * inv;
      xs[gg][4 * tid + 1] = ((p0.y + p1v.y) + (p2v.y + p3v.y)) * inv;
      xs[gg][4 * tid + 2] = ((p0.z + p1v.z) + (p2v.z + p3v.z)) * inv;
      xs[gg][4 * tid + 3] = ((p0.w + p1v.w) + (p2v.w + p3v.w)) * inv;
    }
    __syncthreads();
  }

  // ---- Phase C1: pool  g = gelu(mean @ pool_w + pool_b) ----
  {
    const int j = tid;
    float a0 = 0.f, a1 = 0.f;
#pragma unroll 8
    for (int k = 0; k < 256; ++k) {
      const float w = pool_w[k * 256 + j];
      a0 += xs[0][k] * w;
      a1 += xs[1][k] * w;
    }
    const float bj = pool_b[j];
    a0 = gelu_exact(a0 + bj);
    a1 = gelu_exact(a1 + bj);
    __syncthreads();  // all reads of xs (means) complete before overwrite
    xs[0][j] = a0;
    xs[1][j] = a1;
    out[OFF_G + (g0 + 0) * 256 + j] = a0;
    out[OFF_G + (g0 + 1) * 256 + j] = a1;
  }
  __syncthreads();

  // ---- Phase C2: ec1 head ----
  {
    const int r = tid >> 7, j = tid & 127;
    float a = 0.f;
#pragma unroll 8
    for (int k = 0; k < 256; ++k) a += xs[r][k] * w11[k * 128 + j];
    hs[r][j] = gelu_exact(a + b11[j]);
  }
  __syncthreads();
  if (tid < 2 * E1) {
    const int r2 = tid / E1, j2 = tid - r2 * E1;
    float acc = b12[j2];
#pragma unroll 8
    for (int k = 0; k < 128; ++k) acc += hs[r2][k] * w12[k * E1 + j2];
    os[r2][j2] = acc;
    out[OFF_L1 + (g0 + r2) * E1 + j2] = acc;
  }
  __syncthreads();
  if (tid < 2) {
    float m = os[tid][0];
    for (int q = 1; q < E1; ++q) m = fmaxf(m, os[tid][q]);
    float s = 0.f;
    for (int q = 0; q < E1; ++q) { float e = expf(os[tid][q] - m); os[tid][q] = e; s += e; }
    const float inv = 1.0f / s;
    for (int q = 0; q < E1; ++q) os[tid][q] *= inv;
  }
  __syncthreads();
  if (tid < 2 * E1) {
    const int r2 = tid / E1, j2 = tid - r2 * E1;
    const float v = os[r2][j2];
    out[OFF_P1 + (g0 + r2) * E1 + j2] = v;
    xs[r2][256 + j2] = v;  // append p1 to concat buffer
  }
  __syncthreads();

  // ---- Phase C3: ec2 head (K = 263) ----
  {
    const int r = tid >> 7, j = tid & 127;
    float a = 0.f;
#pragma unroll 8
    for (int k = 0; k < 256 + E1; ++k) a += xs[r][k] * w21[k * 128 + j];
    hs[r][j] = gelu_exact(a + b21[j]);
  }
  __syncthreads();
  if (tid < 2 * E2) {
    const int r2 = tid / E2, j2 = tid - r2 * E2;
    float acc = b22[j2];
#pragma unroll 8
    for (int k = 0; k < 128; ++k) acc += hs[r2][k] * w22[k * E2 + j2];
    os[r2][j2] = acc;
    out[OFF_L2 + (g0 + r2) * E2 + j2] = acc;
  }
  __syncthreads();
  if (tid < 2) {
    float m = os[tid][0];
    for (int q = 1; q < E2; ++q) m = fmaxf(m, os[tid][q]);
    float s = 0.f;
    for (int q = 0; q < E2; ++q) { float e = expf(os[tid][q] - m); os[tid][q] = e; s += e; }
    const float inv = 1.0f / s;
    for (int q = 0; q < E2; ++q) os[tid][q] *= inv;
  }
  __syncthreads();
  if (tid < 2 * E2) {
    const int r2 = tid / E2, j2 = tid - r2 * E2;
    xs[r2][256 + E1 + j2] = os[r2][j2];  // append p2
  }
  __syncthreads();

  // ---- Phase C4: ec3 head (K = 333) ----
  {
    const int r = tid >> 7, j = tid & 127;
    float a = 0.f;
#pragma unroll 8
    for (int k = 0; k < 256 + E1 + E2; ++k) a += xs[r][k] * w31[k * 128 + j];
    hs[r][j] = gelu_exact(a + b31[j]);
  }
  __syncthreads();
  for (int idx = tid; idx < 2 * E3; idx += 256) {
    const int r2 = idx / E3, j2 = idx - r2 * E3;
    float acc = b32[j2];
#pragma unroll 8
    for (int k = 0; k < 128; ++k) acc += hs[r2][k] * w32[k * E3 + j2];
    out[OFF_L3 + (g0 + r2) * E3 + j2] = acc;
  }
}

// ---------------------------------------------------------------------------
extern "C" void kernel_launch(void* const* d_in, const int* in_sizes, int n_in,
                              void* d_out, int out_size, void* d_ws, size_t ws_size,
                              hipStream_t stream) {
  const float* emb    = (const float*)d_in[0];
  const int*   bidx   = (const int*)d_in[1];
  const float* pool_w = (const float*)d_in[2];
  const float* pool_b = (const float*)d_in[3];
  const float* w11    = (const float*)d_in[4];
  const float* b11    = (const float*)d_in[5];
  const float* w12    = (const float*)d_in[6];
  const float* b12    = (const float*)d_in[7];
  const float* w21    = (const float*)d_in[8];
  const float* b21    = (const float*)d_in[9];
  const float* w22    = (const float*)d_in[10];
  const float* b22    = (const float*)d_in[11];
  const float* w31    = (const float*)d_in[12];
  const float* b31    = (const float*)d_in[13];
  const float* w32    = (const float*)d_in[14];
  const float* b32    = (const float*)d_in[15];
  float* out = (float*)d_out;

  fused_kernel<<<GG / 2, 256, 0, stream>>>(
      emb, bidx, pool_w, pool_b, w11, b11, w12, b12,
      w21, b21, w22, b22, w31, b31, w32, b32, out);
}

// Round 6
// 113.759 us; speedup vs baseline: 2.0149x; 1.7320x over previous
//
#include <hip/hip_runtime.h>
#include <hip/hip_bf16.h>
#include <math.h>

// ---------------------------------------------------------------------------
// Problem shapes
// ---------------------------------------------------------------------------
#define NN 400000
#define GG 1024
#define E1 7
#define E2 70
#define E3 300

// Output layout (flat f32)
#define OFF_L1 0
#define OFF_L2 7168
#define OFF_L3 78848
#define OFF_P1 386048
#define OFF_G  393216

typedef float f32x4 __attribute__((ext_vector_type(4)));

__device__ __forceinline__ float gelu_exact(float v) {
  return 0.5f * v * (1.0f + erff(v * 0.70710678118654752f));
}

// ---------------------------------------------------------------------------
// ONE fused kernel (R5 structure, single change: NON-TEMPORAL emb loads).
// Block b owns graphs {2b, 2b+1}: bounds search -> segment mean -> MLP.
// ---------------------------------------------------------------------------
__global__ __launch_bounds__(256) void fused_kernel(
    const float* __restrict__ emb, const int* __restrict__ bidx,
    const float* __restrict__ pool_w, const float* __restrict__ pool_b,
    const float* __restrict__ w11, const float* __restrict__ b11,
    const float* __restrict__ w12, const float* __restrict__ b12,
    const float* __restrict__ w21, const float* __restrict__ b21,
    const float* __restrict__ w22, const float* __restrict__ b22,
    const float* __restrict__ w31, const float* __restrict__ b31,
    const float* __restrict__ w32, const float* __restrict__ b32,
    float* __restrict__ out) {
  const int g0 = blockIdx.x * 2;
  const int tid = threadIdx.x;
  const int wave = tid >> 6, lane = tid & 63;

  __shared__ int seg[3];
  __shared__ float xs[2][336];   // concat activations: g | p1 | p2 (K up to 333)
  __shared__ float hs[2][128];   // hidden
  __shared__ float os[2][72];    // head logits (up to E2) for softmax
  __shared__ f32x4 red[4][64];   // cross-wave reduction

  // ---- Phase A: segment bounds ----
  if (tid < 3) {
    const int target = g0 + tid;
    int lo = 0, hi = NN;
    while (lo < hi) {
      int mid = (lo + hi) >> 1;
      if (bidx[mid] < target) lo = mid + 1; else hi = mid;
    }
    seg[tid] = lo;
  }
  __syncthreads();

  // ---- Phase B: mean for each of the 2 graphs (nt streaming loads) ----
  for (int gg = 0; gg < 2; ++gg) {
    const int start = seg[gg], end = seg[gg + 1];
    const int hn = end - start;
    // this wave's contiguous quarter
    const int q0 = start + (hn * wave) / 4;
    const int q1 = start + (hn * (wave + 1)) / 4;
    const f32x4* __restrict__ p = (const f32x4*)emb + (size_t)q0 * 64 + lane;
    int n = q1 - q0;

    f32x4 a0 = {0.f, 0.f, 0.f, 0.f};
    f32x4 a1 = a0, a2 = a0, a3 = a0, a4 = a0, a5 = a0, a6 = a0, a7 = a0;
    for (; n >= 8; n -= 8, p += 512) {
      f32x4 v0 = __builtin_nontemporal_load(p + 0);
      f32x4 v1 = __builtin_nontemporal_load(p + 64);
      f32x4 v2 = __builtin_nontemporal_load(p + 128);
      f32x4 v3 = __builtin_nontemporal_load(p + 192);
      f32x4 v4 = __builtin_nontemporal_load(p + 256);
      f32x4 v5 = __builtin_nontemporal_load(p + 320);
      f32x4 v6 = __builtin_nontemporal_load(p + 384);
      f32x4 v7 = __builtin_nontemporal_load(p + 448);
      a0 += v0; a1 += v1; a2 += v2; a3 += v3;
      a4 += v4; a5 += v5; a6 += v6; a7 += v7;
    }
    for (; n > 0; --n, p += 64) {
      a0 += __builtin_nontemporal_load(p);
    }
    a0 += a1; a2 += a3; a4 += a5; a6 += a7;
    a0 += a2; a4 += a6;
    a0 += a4;

    red[wave][lane] = a0;
    __syncthreads();
    if (tid < 64) {
      f32x4 s = ((red[0][tid] + red[1][tid]) + (red[2][tid] + red[3][tid]));
      const float inv = 1.0f / (float)max(hn, 1);
      s *= inv;
      xs[gg][4 * tid + 0] = s.x;
      xs[gg][4 * tid + 1] = s.y;
      xs[gg][4 * tid + 2] = s.z;
      xs[gg][4 * tid + 3] = s.w;
    }
    __syncthreads();
  }

  // ---- Phase C1: pool  g = gelu(mean @ pool_w + pool_b) ----
  {
    const int j = tid;
    float a0 = 0.f, a1 = 0.f;
#pragma unroll 8
    for (int k = 0; k < 256; ++k) {
      const float w = pool_w[k * 256 + j];
      a0 += xs[0][k] * w;
      a1 += xs[1][k] * w;
    }
    const float bj = pool_b[j];
    a0 = gelu_exact(a0 + bj);
    a1 = gelu_exact(a1 + bj);
    __syncthreads();  // all reads of xs (means) complete before overwrite
    xs[0][j] = a0;
    xs[1][j] = a1;
    out[OFF_G + (g0 + 0) * 256 + j] = a0;
    out[OFF_G + (g0 + 1) * 256 + j] = a1;
  }
  __syncthreads();

  // ---- Phase C2: ec1 head ----
  {
    const int r = tid >> 7, j = tid & 127;
    float a = 0.f;
#pragma unroll 8
    for (int k = 0; k < 256; ++k) a += xs[r][k] * w11[k * 128 + j];
    hs[r][j] = gelu_exact(a + b11[j]);
  }
  __syncthreads();
  if (tid < 2 * E1) {
    const int r2 = tid / E1, j2 = tid - r2 * E1;
    float acc = b12[j2];
#pragma unroll 8
    for (int k = 0; k < 128; ++k) acc += hs[r2][k] * w12[k * E1 + j2];
    os[r2][j2] = acc;
    out[OFF_L1 + (g0 + r2) * E1 + j2] = acc;
  }
  __syncthreads();
  if (tid < 2) {
    float m = os[tid][0];
    for (int q = 1; q < E1; ++q) m = fmaxf(m, os[tid][q]);
    float s = 0.f;
    for (int q = 0; q < E1; ++q) { float e = expf(os[tid][q] - m); os[tid][q] = e; s += e; }
    const float inv = 1.0f / s;
    for (int q = 0; q < E1; ++q) os[tid][q] *= inv;
  }
  __syncthreads();
  if (tid < 2 * E1) {
    const int r2 = tid / E1, j2 = tid - r2 * E1;
    const float v = os[r2][j2];
    out[OFF_P1 + (g0 + r2) * E1 + j2] = v;
    xs[r2][256 + j2] = v;  // append p1 to concat buffer
  }
  __syncthreads();

  // ---- Phase C3: ec2 head (K = 263) ----
  {
    const int r = tid >> 7, j = tid & 127;
    float a = 0.f;
#pragma unroll 8
    for (int k = 0; k < 256 + E1; ++k) a += xs[r][k] * w21[k * 128 + j];
    hs[r][j] = gelu_exact(a + b21[j]);
  }
  __syncthreads();
  if (tid < 2 * E2) {
    const int r2 = tid / E2, j2 = tid - r2 * E2;
    float acc = b22[j2];
#pragma unroll 8
    for (int k = 0; k < 128; ++k) acc += hs[r2][k] * w22[k * E2 + j2];
    os[r2][j2] = acc;
    out[OFF_L2 + (g0 + r2) * E2 + j2] = acc;
  }
  __syncthreads();
  if (tid < 2) {
    float m = os[tid][0];
    for (int q = 1; q < E2; ++q) m = fmaxf(m, os[tid][q]);
    float s = 0.f;
    for (int q = 0; q < E2; ++q) { float e = expf(os[tid][q] - m); os[tid][q] = e; s += e; }
    const float inv = 1.0f / s;
    for (int q = 0; q < E2; ++q) os[tid][q] *= inv;
  }
  __syncthreads();
  if (tid < 2 * E2) {
    const int r2 = tid / E2, j2 = tid - r2 * E2;
    xs[r2][256 + E1 + j2] = os[r2][j2];  // append p2
  }
  __syncthreads();

  // ---- Phase C4: ec3 head (K = 333) ----
  {
    const int r = tid >> 7, j = tid & 127;
    float a = 0.f;
#pragma unroll 8
    for (int k = 0; k < 256 + E1 + E2; ++k) a += xs[r][k] * w31[k * 128 + j];
    hs[r][j] = gelu_exact(a + b31[j]);
  }
  __syncthreads();
  for (int idx = tid; idx < 2 * E3; idx += 256) {
    const int r2 = idx / E3, j2 = idx - r2 * E3;
    float acc = b32[j2];
#pragma unroll 8
    for (int k = 0; k < 128; ++k) acc += hs[r2][k] * w32[k * E3 + j2];
    out[OFF_L3 + (g0 + r2) * E3 + j2] = acc;
  }
}

// ---------------------------------------------------------------------------
extern "C" void kernel_launch(void* const* d_in, const int* in_sizes, int n_in,
                              void* d_out, int out_size, void* d_ws, size_t ws_size,
                              hipStream_t stream) {
  const float* emb    = (const float*)d_in[0];
  const int*   bidx   = (const int*)d_in[1];
  const float* pool_w = (const float*)d_in[2];
  const float* pool_b = (const float*)d_in[3];
  const float* w11    = (const float*)d_in[4];
  const float* b11    = (const float*)d_in[5];
  const float* w12    = (const float*)d_in[6];
  const float* b12    = (const float*)d_in[7];
  const float* w21    = (const float*)d_in[8];
  const float* b21    = (const float*)d_in[9];
  const float* w22    = (const float*)d_in[10];
  const float* b22    = (const float*)d_in[11];
  const float* w31    = (const float*)d_in[12];
  const float* b31    = (const float*)d_in[13];
  const float* w32    = (const float*)d_in[14];
  const float* b32    = (const float*)d_in[15];
  float* out = (float*)d_out;

  fused_kernel<<<GG / 2, 256, 0, stream>>>(
      emb, bidx, pool_w, pool_b, w11, b11, w12, b12,
      w21, b21, w22, b22, w31, b31, w32, b32, out);
}